// Round 5
// baseline (109.127 us; speedup 1.0000x reference)
//
#include <hip/hip_runtime.h>

// Retention forward, chunkwise-linear, 2 stream-ordered kernels (1 boundary).
//   p12: grid (16 groups-of-2-chunks, 32 bh) = 512 blocks (2/CU), serial depth 2.
//        Per group: U via MFMA, register scan -> U_{2g} (= L for odd chunks) and
//        T_g = lamC*U_{2g}+U_{2g+1} (g<15), bf16. ALSO relays V^T bf16 tiles
//        (pre-swizzled granules) so the consumer never reads fp32 V.
//   p3 : intra + cross; S_c = [c odd: U_{c-1}] + sum_{g'<g} lamC^(c-2g'-2) T_g'
//        (<=16 L2-hot terms; 7-term combine measured free in r1). V staged via
//        global_load_lds dwordx4 from the relay (zero VALU), XOR-swizzled reads.
// Measured design rules:
//   - grid.sync ~430us @1024 blocks — never. Cross-block flag/spin sync: 3x
//     regression, MfmaUtil 0.4% (r2) — never. Quadratic 31-term U re-scan — never.
//   - dispatch boundary ~6-7us each (r0/r1/r3 fits); 2 dispatches optimal, but
//     producer serial depth 4 eats the saving (r1) -> depth 2 here.
//   - reset fill (256MiB, ~41.5us, in timed region) evicts L3 every iter: all
//     input reads are HBM-cold; never read an input twice (r4 double-K: -2us).
//   - bf16 intermediates fine: threshold 4.46, measured absmax 1.0.

#define S_LEN 2048
#define DHEAD 64
#define CHUNK 64
#define NC    32
#define NG    16
#define BH    32
#define LDK   72

typedef float  f32x4  __attribute__((ext_vector_type(4)));
typedef short  bf16x8 __attribute__((ext_vector_type(8)));
typedef unsigned short u16x8 __attribute__((ext_vector_type(8)));
typedef unsigned short u16x4 __attribute__((ext_vector_type(4)));

static __device__ __forceinline__ unsigned short f2bf(float f) {
    unsigned int u = __float_as_uint(f);
    u += 0x7FFFu + ((u >> 16) & 1u);
    return (unsigned short)(u >> 16);
}
static __device__ __forceinline__ float bf2f(unsigned short h) {
    return __uint_as_float((unsigned int)h << 16);
}

// async global->LDS, 16B per lane; lds ptr must be wave-uniform (HW adds lane*16)
#define GLDS16(gp_, lp_) __builtin_amdgcn_global_load_lds( \
    (const __attribute__((address_space(1))) void*)(gp_),  \
    (__attribute__((address_space(3))) void*)(lp_), 16, 0, 0)

// ---------------- p12: depth-2 group scan + V^T bf16 relay ----------------
__global__ __launch_bounds__(256)
void ret_p12(const float* __restrict__ kg, const float* __restrict__ vg,
             unsigned short* __restrict__ Ue, unsigned short* __restrict__ Tb,
             unsigned short* __restrict__ Vr) {
    const int g  = (int)blockIdx.x, bh = (int)blockIdx.y, h = bh & 15;
    const int tid = (int)threadIdx.x;
    const int wv = tid >> 6, ln = tid & 63, quad = ln >> 4, lnlo = ln & 15;
    const float sh   = log2f(1.0f - exp2f(-5.0f - (float)h));   // < 0
    const float lamC = exp2f(sh * (float)CHUNK);

    __shared__ __align__(16) unsigned short Kt[CHUNK * LDK];  // lam-weighted K^T [d][j]
    __shared__ __align__(16) unsigned short Vt[CHUNK * LDK];  // V^T [e][j]

    const size_t bb = (size_t)bh * S_LEN * DHEAD;

    float rk[2][8], rv[2][8];
    {   // load chunk 2g
        const size_t cb0 = bb + (size_t)(2 * g) * CHUNK * DHEAD;
#pragma unroll
        for (int i2 = 0; i2 < 2; ++i2) {
            const int pos0 = wv * 8 + i2 * 32;
            const float* pK = kg + cb0 + (size_t)pos0 * DHEAD + ln;
            const float* pV = vg + cb0 + (size_t)pos0 * DHEAD + ln;
#pragma unroll
            for (int j = 0; j < 8; ++j) {
                rk[i2][j] = pK[(size_t)j * DHEAD];
                rv[i2][j] = pV[(size_t)j * DHEAD];
            }
        }
    }

    f32x4 Sreg[4];  // fragment layout: e = nt*16+lnlo, d = wv*16+quad*4+r
#pragma unroll
    for (int nt = 0; nt < 4; ++nt) Sreg[nt] = (f32x4){0.f, 0.f, 0.f, 0.f};

#pragma unroll
    for (int i = 0; i < 2; ++i) {
        const int c = 2 * g + i;
        // stage weighted K^T + V^T; relay V^T granules (pre-swizzled) to global
        unsigned short* vt = Vr + ((size_t)(bh * NC + c) << 12);
#pragma unroll
        for (int i2 = 0; i2 < 2; ++i2) {
            const int pos0 = wv * 8 + i2 * 32;
            u16x8 tk, tv;
#pragma unroll
            for (int j = 0; j < 8; ++j) {
                const float w = exp2f(sh * (float)(CHUNK - pos0 - j));  // lam^(C - j_local)
                tk[j] = f2bf(rk[i2][j] * w);
                tv[j] = f2bf(rv[i2][j]);
            }
            *(u16x8*)&Kt[ln * LDK + pos0] = tk;
            *(u16x8*)&Vt[ln * LDK + pos0] = tv;
            const int ri = (ln * 64 + pos0) ^ ((ln & 7) << 3);  // granule XOR swizzle
            *(u16x8*)&vt[ri] = tv;
        }
        __syncthreads();

        if (i == 0) {  // prefetch chunk 2g+1 under the MFMAs
            const size_t cbn = bb + (size_t)(2 * g + 1) * CHUNK * DHEAD;
#pragma unroll
            for (int i2 = 0; i2 < 2; ++i2) {
                const int pos0 = wv * 8 + i2 * 32;
                const float* pK = kg + cbn + (size_t)pos0 * DHEAD + ln;
                const float* pV = vg + cbn + (size_t)pos0 * DHEAD + ln;
#pragma unroll
                for (int j = 0; j < 8; ++j) {
                    rk[i2][j] = pK[(size_t)j * DHEAD];
                    rv[i2][j] = pV[(size_t)j * DHEAD];
                }
            }
        }

        bf16x8 aK[2];
#pragma unroll
        for (int ks = 0; ks < 2; ++ks)
            aK[ks] = *(const bf16x8*)&Kt[(wv * 16 + lnlo) * LDK + ks * 32 + quad * 8];
#pragma unroll
        for (int nt = 0; nt < 4; ++nt) {
            f32x4 a = (f32x4){0.f, 0.f, 0.f, 0.f};
#pragma unroll
            for (int ks = 0; ks < 2; ++ks) {
                const bf16x8 bv = *(const bf16x8*)&Vt[(nt * 16 + lnlo) * LDK + ks * 32 + quad * 8];
                a = __builtin_amdgcn_mfma_f32_16x16x32_bf16(aK[ks], bv, a, 0, 0, 0);
            }
#pragma unroll
            for (int r = 0; r < 4; ++r) Sreg[nt][r] = lamC * Sreg[nt][r] + a[r];
        }
        __syncthreads();

        if (i == 0) {   // U_{2g}: serves as S-contribution (weight 1) for chunk 2g+1
            unsigned short* up = Ue + ((size_t)(bh * NG + g) << 12);
#pragma unroll
            for (int nt = 0; nt < 4; ++nt) {
                u16x4 w;
#pragma unroll
                for (int r = 0; r < 4; ++r) w[r] = f2bf(Sreg[nt][r]);
                *(u16x4*)&up[(nt * 16 + lnlo) * 64 + wv * 16 + quad * 4] = w;
            }
        } else if (g < NG - 1) {   // T_g = lamC*U_{2g} + U_{2g+1}
            unsigned short* tp = Tb + ((size_t)(bh * NG + g) << 12);
#pragma unroll
            for (int nt = 0; nt < 4; ++nt) {
                u16x4 w;
#pragma unroll
                for (int r = 0; r < 4; ++r) w[r] = f2bf(Sreg[nt][r]);
                *(u16x4*)&tp[(nt * 16 + lnlo) * 64 + wv * 16 + quad * 4] = w;
            }
        }
    }
}

// ---------------- p3: intra + cross (<=16-term S build, relayed V) ----------------
__global__ __launch_bounds__(256)
void ret_p3(const float* __restrict__ qg, const float* __restrict__ kg,
            const unsigned short* __restrict__ Ue, const unsigned short* __restrict__ Tb,
            const unsigned short* __restrict__ Vr, float* __restrict__ og) {
    const int c  = (int)blockIdx.x, bh = (int)blockIdx.y, h = bh & 15;
    const int tid = (int)threadIdx.x;
    const int wv = tid >> 6, ln = tid & 63, quad = ln >> 4, lnlo = ln & 15;
    const float sh    = log2f(1.0f - exp2f(-5.0f - (float)h));
    const float scale = 0.125f;
    const int g = c >> 1;

    // Ks 64x72 (9216B) | Vt 64x64 swizzled (8192B) | ShL 64x72 (9216B)
    __shared__ __align__(16) unsigned short smem[CHUNK * LDK + CHUNK * 64 + CHUNK * LDK];
    unsigned short* const Ks  = smem;
    unsigned short* const Vt  = smem + CHUNK * LDK;
    unsigned short* const ShL = smem + CHUNK * LDK + CHUNK * 64;

    const size_t cb = (size_t)bh * S_LEN * DHEAD + (size_t)c * CHUNK * DHEAD;
    const float* qp = qg + cb;
    const float* kp = kg + cb;
    float*       op = og + cb;

    // ---- stage V^T: async copy of pre-swizzled relay tile (linear dest) ----
    {
        const unsigned short* vt = Vr + ((size_t)(bh * NC + c) << 12);
        const int wbase = wv * 1024;              // u16 units; wave-uniform
        GLDS16(vt + wbase + ln * 8,       &Vt[wbase]);
        GLDS16(vt + wbase + 512 + ln * 8, &Vt[wbase + 512]);
    }
    // ---- stage K [pos][d] ----
    {
        const int kr = tid >> 2, kc0 = (tid & 3) * 16;
        const float* p = kp + (size_t)kr * DHEAD + kc0;
        const f32x4 x0 = *(const f32x4*)(p + 0);
        const f32x4 x1 = *(const f32x4*)(p + 4);
        const f32x4 x2 = *(const f32x4*)(p + 8);
        const f32x4 x3 = *(const f32x4*)(p + 12);
        u16x8 w0, w1;
        w0[0]=f2bf(x0[0]); w0[1]=f2bf(x0[1]); w0[2]=f2bf(x0[2]); w0[3]=f2bf(x0[3]);
        w0[4]=f2bf(x1[0]); w0[5]=f2bf(x1[1]); w0[6]=f2bf(x1[2]); w0[7]=f2bf(x1[3]);
        w1[0]=f2bf(x2[0]); w1[1]=f2bf(x2[1]); w1[2]=f2bf(x2[2]); w1[3]=f2bf(x2[3]);
        w1[4]=f2bf(x3[0]); w1[5]=f2bf(x3[1]); w1[6]=f2bf(x3[2]); w1[7]=f2bf(x3[3]);
        *(u16x8*)&Ks[kr * LDK + kc0]     = w0;
        *(u16x8*)&Ks[kr * LDK + kc0 + 8] = w1;
    }
    // ---- stage S^T = [c odd: U_{c-1}] + sum_{g'<g} lamC^(c-2g'-2) T_g' ----
    {
        const int r = tid >> 2, ccol = (tid & 3) * 16;
        float accS[16];
        if (c & 1) {
            const unsigned short* lp = Ue + ((size_t)(bh * NG + g) << 12) + (size_t)tid * 16;
            const u16x8 a0 = *(const u16x8*)lp;
            const u16x8 a1 = *(const u16x8*)(lp + 8);
#pragma unroll
            for (int j = 0; j < 8; ++j) { accS[j] = bf2f(a0[j]); accS[8 + j] = bf2f(a1[j]); }
        } else {
#pragma unroll
            for (int j = 0; j < 16; ++j) accS[j] = 0.f;
        }
        for (int gp = 0; gp < g; ++gp) {   // block-uniform trip count; T tiles L2/L3-hot
            const float w = exp2f(sh * (float)(CHUNK * (c - 2 * gp - 2)));
            const unsigned short* tp = Tb + ((size_t)(bh * NG + gp) << 12) + (size_t)tid * 16;
            const u16x8 t0 = *(const u16x8*)tp;
            const u16x8 t1 = *(const u16x8*)(tp + 8);
#pragma unroll
            for (int j = 0; j < 8; ++j) { accS[j] += w * bf2f(t0[j]); accS[8 + j] += w * bf2f(t1[j]); }
        }
        u16x8 w0, w1;
#pragma unroll
        for (int j = 0; j < 8; ++j) { w0[j] = f2bf(accS[j]); w1[j] = f2bf(accS[8 + j]); }
        *(u16x8*)&ShL[r * LDK + ccol]     = w0;
        *(u16x8*)&ShL[r * LDK + ccol + 8] = w1;
    }

    // ---- Q A-fragments ----
    bf16x8 aQ[2];
    {
        const float* qrow = qp + (size_t)(wv * 16 + lnlo) * DHEAD;
#pragma unroll
        for (int ks = 0; ks < 2; ++ks) {
            const float* p = qrow + ks * 32 + quad * 8;
            bf16x8 a;
#pragma unroll
            for (int j = 0; j < 8; ++j) a[j] = (short)f2bf(p[j]);
            aQ[ks] = a;
        }
    }
    float rf[4];
#pragma unroll
    for (int r = 0; r < 4; ++r) rf[r] = exp2f((float)(wv * 16 + quad * 4 + r) * sh);

    __syncthreads();   // drains ds_writes AND the async global_load_lds (vmcnt)

    // ---- cross: o = Q.S ----
    f32x4 o[4];
#pragma unroll
    for (int nt = 0; nt < 4; ++nt) {
        f32x4 a = (f32x4){0.f, 0.f, 0.f, 0.f};
#pragma unroll
        for (int ks = 0; ks < 2; ++ks) {
            const bf16x8 bs = *(const bf16x8*)&ShL[(nt * 16 + lnlo) * LDK + ks * 32 + quad * 8];
            a = __builtin_amdgcn_mfma_f32_16x16x32_bf16(aQ[ks], bs, a, 0, 0, 0);
        }
        o[nt] = a;
    }

    // ---- intra scores ----
    f32x4 acc[4];
#pragma unroll
    for (int nt = 0; nt < 4; ++nt) {
        f32x4 a = (f32x4){0.f, 0.f, 0.f, 0.f};
#pragma unroll
        for (int ks = 0; ks < 2; ++ks) {
            const bf16x8 bk = *(const bf16x8*)&Ks[(nt * 16 + lnlo) * LDK + ks * 32 + quad * 8];
            a = __builtin_amdgcn_mfma_f32_16x16x32_bf16(aQ[ks], bk, a, 0, 0, 0);
        }
        acc[nt] = a;
    }

    // scale cross by scale * lam^(i_local)
#pragma unroll
    for (int nt = 0; nt < 4; ++nt)
#pragma unroll
        for (int r = 0; r < 4; ++r) o[nt][r] *= rf[r] * scale;

    __syncthreads();   // all waves done reading ShL before it becomes Ws

    // ---- decay*scale*causal; C-layout -> A-layout via LDS (same-wave rows) ----
#pragma unroll
    for (int nt = 0; nt < 4; ++nt) {
        const int jn = nt * 16 + lnlo;
        const float cf = scale * exp2f(-(float)jn * sh);
#pragma unroll
        for (int r = 0; r < 4; ++r) {
            const int ri = wv * 16 + quad * 4 + r;
            float wgt = acc[nt][r] * rf[r] * cf;
            if (ri < jn) wgt = 0.0f;
            ShL[ri * LDK + jn] = f2bf(wgt);
        }
    }
    const bf16x8 aW0 = *(const bf16x8*)&ShL[(wv * 16 + lnlo) * LDK + quad * 8];
    const bf16x8 aW1 = *(const bf16x8*)&ShL[(wv * 16 + lnlo) * LDK + 32 + quad * 8];

    // ---- O += P V (swizzled Vt reads, stride 64, XOR (row&7)<<3 granules) ----
#pragma unroll
    for (int nt = 0; nt < 4; ++nt) {
        const int row = nt * 16 + lnlo;
        const int sw  = (row & 7) << 3;
        const bf16x8 bv0 = *(const bf16x8*)&Vt[(row * 64 + quad * 8) ^ sw];
        const bf16x8 bv1 = *(const bf16x8*)&Vt[(row * 64 + 32 + quad * 8) ^ sw];
        o[nt] = __builtin_amdgcn_mfma_f32_16x16x32_bf16(aW0, bv0, o[nt], 0, 0, 0);
        o[nt] = __builtin_amdgcn_mfma_f32_16x16x32_bf16(aW1, bv1, o[nt], 0, 0, 0);
    }

    // ---- epilogue: bounce through LDS -> coalesced dwordx4 stores ----
    __syncthreads();   // all waves done with Ks/Vt/ShL before overlay
    float* const Of = (float*)smem;   // 64 x 68 fp32 = 17408 B = Ks+Vt exactly
#pragma unroll
    for (int nt = 0; nt < 4; ++nt)
#pragma unroll
        for (int r = 0; r < 4; ++r)
            Of[(wv * 16 + quad * 4 + r) * 68 + nt * 16 + lnlo] = o[nt][r];
    // rows [wv*16, wv*16+16) written and read by the same wave -> no barrier
    {
        const int row = tid >> 2, col0 = (tid & 3) * 16;
        const float* src = &Of[row * 68 + col0];
        float* dst = op + (size_t)row * DHEAD + col0;
        *(f32x4*)(dst + 0)  = *(const f32x4*)(src + 0);
        *(f32x4*)(dst + 4)  = *(const f32x4*)(src + 4);
        *(f32x4*)(dst + 8)  = *(const f32x4*)(src + 8);
        *(f32x4*)(dst + 12) = *(const f32x4*)(src + 12);
    }
}

extern "C" void kernel_launch(void* const* d_in, const int* in_sizes, int n_in,
                              void* d_out, int out_size, void* d_ws, size_t ws_size,
                              hipStream_t stream) {
    (void)in_sizes; (void)n_in; (void)out_size; (void)ws_size;
    const float* q = (const float*)d_in[0];
    const float* k = (const float*)d_in[1];
    const float* v = (const float*)d_in[2];
    float* o  = (float*)d_out;
    unsigned short* Ue = (unsigned short*)d_ws;                          // 4 MB: U_{2g} tiles
    unsigned short* Tb = (unsigned short*)((char*)d_ws + ( 4u << 20));   // 4 MB: T_g tiles
    unsigned short* Vr = (unsigned short*)((char*)d_ws + ( 8u << 20));   // 8 MB: V^T bf16 relay (swizzled)

    dim3 blk(256, 1, 1);
    ret_p12<<<dim3(NG, BH, 1), blk, 0, stream>>>(k, v, Ue, Tb, Vr);
    ret_p3 <<<dim3(NC, BH, 1), blk, 0, stream>>>(q, k, Ue, Tb, Vr, o);
}

// Round 6
// 107.531 us; speedup vs baseline: 1.0148x; 1.0148x over previous
//
#include <hip/hip_runtime.h>

// Retention forward, chunkwise-linear, 3 wide-shallow stream-ordered kernels (r0 frame).
//   p1: U_c[e][d] = sum_j lam^(C-j) K[j][d] V[j][e]  (MFMA, chunks 0..30) -> bf16
//   p2: linear scan S_c = lamC*S_{c-1} + U_{c-1}, FULLY UNROLLED: 31 independent
//       compile-time-offset loads (compiler hoists; L3-hot) + 31-FMA chain.
//   p3: intra + cross. 4-segment LDS (Ks|Vt|ShL|Ws, 36864B, still 4 blk/CU = grid
//       occupancy) -> mid-kernel barrier removed (Ws same-wave-slab RAW only).
// Measured design rules:
//   - grid.sync ~430us @1024 blocks — never. Cross-block flag/spin sync: 3x
//     regression, MfmaUtil 0.4% (r2) — never. Quadratic 31-term U re-scan — never.
//   - producer restructures don't pay: r1 depth-4 (=r0), r4 e-split (+2), r5
//     depth-2+relay (+5, scatter stores); r3 extra boundary (+7). r0 frame wins.
//   - reset fill (256MiB, ~41.5us, in timed region) evicts L3 every iter: inputs
//     HBM-cold, never read twice; workspace written post-fill is L3-hot.
//   - bf16 intermediates fine: threshold 4.46, measured absmax 1.0.

#define S_LEN 2048
#define DHEAD 64
#define CHUNK 64
#define NC    32
#define BH    32
#define LDK   72

typedef float  f32x4  __attribute__((ext_vector_type(4)));
typedef short  bf16x8 __attribute__((ext_vector_type(8)));
typedef unsigned short u16x8 __attribute__((ext_vector_type(8)));
typedef unsigned short u16x4 __attribute__((ext_vector_type(4)));

static __device__ __forceinline__ unsigned short f2bf(float f) {
    unsigned int u = __float_as_uint(f);
    u += 0x7FFFu + ((u >> 16) & 1u);
    return (unsigned short)(u >> 16);
}
static __device__ __forceinline__ float bf2f(unsigned short h) {
    return __uint_as_float((unsigned int)h << 16);
}

// ---------------- Phase 1: per-chunk KV summaries (U^T [e][d] bf16) ----------------
__global__ __launch_bounds__(256)
void ret_p1(const float* __restrict__ kg, const float* __restrict__ vg,
            unsigned short* __restrict__ Ug) {
    const int c  = (int)blockIdx.x, bh = (int)blockIdx.y, h = bh & 15;
    const int tid = (int)threadIdx.x;
    const int wv = tid >> 6, ln = tid & 63, quad = ln >> 4, lnlo = ln & 15;
    const float sh = log2f(1.0f - exp2f(-5.0f - (float)h));   // < 0

    __shared__ __align__(16) unsigned short Kt[CHUNK * LDK];  // lam-weighted K^T [d][j]
    __shared__ __align__(16) unsigned short Vt[CHUNK * LDK];  // V^T [e][j]

    const size_t cb = (size_t)bh * S_LEN * DHEAD + (size_t)c * CHUNK * DHEAD;
    const float* kp = kg + cb;
    const float* vp = vg + cb;

#pragma unroll
    for (int i = 0; i < 2; ++i) {
        const int pos0 = wv * 8 + i * 32;
        const float* pK = kp + (size_t)pos0 * DHEAD + ln;
        const float* pV = vp + (size_t)pos0 * DHEAD + ln;
        u16x8 tk, tv;
#pragma unroll
        for (int j = 0; j < 8; ++j) {
            const float w = exp2f(sh * (float)(CHUNK - pos0 - j));  // lam^(C - j_local)
            tk[j] = f2bf(pK[(size_t)j * DHEAD] * w);
            tv[j] = f2bf(pV[(size_t)j * DHEAD]);
        }
        *(u16x8*)&Kt[ln * LDK + pos0] = tk;
        *(u16x8*)&Vt[ln * LDK + pos0] = tv;
    }
    __syncthreads();

    bf16x8 aK[2];
#pragma unroll
    for (int ks = 0; ks < 2; ++ks)
        aK[ks] = *(const bf16x8*)&Kt[(wv * 16 + lnlo) * LDK + ks * 32 + quad * 8];

    unsigned short* up = Ug + ((size_t)(bh * NC + c) << 12);
#pragma unroll
    for (int nt = 0; nt < 4; ++nt) {
        f32x4 acc = (f32x4){0.f, 0.f, 0.f, 0.f};
#pragma unroll
        for (int ks = 0; ks < 2; ++ks) {
            const bf16x8 bv = *(const bf16x8*)&Vt[(nt * 16 + lnlo) * LDK + ks * 32 + quad * 8];
            acc = __builtin_amdgcn_mfma_f32_16x16x32_bf16(aK[ks], bv, acc, 0, 0, 0);
        }
        // U^T[e][d]: e = nt*16+lnlo, d = wv*16+quad*4+r  (8B store per lane)
        u16x4 w;
#pragma unroll
        for (int r = 0; r < 4; ++r) w[r] = f2bf(acc[r]);
        *(u16x4*)&up[(nt * 16 + lnlo) * 64 + wv * 16 + quad * 4] = w;
    }
}

// ---------------- Phase 2: linear scan, fully unrolled ----------------
// All 31 loads are independent compile-time offsets (compiler hoists; U is
// L3-hot, written by p1 after the reset fill). Chain = 1 load latency + 31 FMA.
__global__ __launch_bounds__(256)
void ret_p2(const unsigned short* __restrict__ Ug, unsigned short* __restrict__ Sg) {
    const int eb = (int)blockIdx.x, bh = (int)blockIdx.y, h = bh & 15;
    const float sh   = log2f(1.0f - exp2f(-5.0f - (float)h));
    const float lamC = exp2f(sh * (float)CHUNK);
    const int elem = eb * 256 + (int)threadIdx.x;

    const unsigned short* up = Ug + ((size_t)(bh * NC) << 12) + elem;
    unsigned short*       sp = Sg + ((size_t)(bh * NC) << 12) + elem;

    float S = 0.0f;
#pragma unroll
    for (int c = 0; c < NC; ++c) {
        sp[(size_t)c << 12] = f2bf(S);           // S_c = prefix before chunk c
        if (c < NC - 1) {                        // U_31 never produced/needed
            const float u = bf2f(up[(size_t)c << 12]);
            S = lamC * S + u;
        }
    }
}

// ---------------- Phase 3: intra + cross (4-segment LDS, 2 barriers) ----------------
__global__ __launch_bounds__(256)
void ret_p3(const float* __restrict__ qg, const float* __restrict__ kg,
            const float* __restrict__ vg, const unsigned short* __restrict__ Sg,
            float* __restrict__ og) {
    const int c  = (int)blockIdx.x, bh = (int)blockIdx.y, h = bh & 15;
    const int tid = (int)threadIdx.x;
    const int wv = tid >> 6, ln = tid & 63, quad = ln >> 4, lnlo = ln & 15;
    const float sh    = log2f(1.0f - exp2f(-5.0f - (float)h));
    const float scale = 0.125f;

    // Ks | Vt | ShL | Ws : 4 x 9216 B = 36864 B -> 4 blocks/CU (= grid's 4/CU)
    __shared__ __align__(16) unsigned short smem[4 * CHUNK * LDK];
    unsigned short* const Ks  = smem;                   // K [pos][d]
    unsigned short* const Vt  = smem + CHUNK * LDK;     // V^T [e][pos]
    unsigned short* const ShL = smem + 2 * CHUNK * LDK; // S^T [e][d]
    unsigned short* const Ws  = smem + 3 * CHUNK * LDK; // decay-weight matrix [i][j]

    const size_t cb = (size_t)bh * S_LEN * DHEAD + (size_t)c * CHUNK * DHEAD;
    const float* qp = qg + cb;
    const float* kp = kg + cb;
    const float* vp = vg + cb;
    float*       op = og + cb;

    // ---- stage K [pos][d] ----
    {
        const int kr = tid >> 2, kc0 = (tid & 3) * 16;
        const float* p = kp + (size_t)kr * DHEAD + kc0;
        const f32x4 x0 = *(const f32x4*)(p + 0);
        const f32x4 x1 = *(const f32x4*)(p + 4);
        const f32x4 x2 = *(const f32x4*)(p + 8);
        const f32x4 x3 = *(const f32x4*)(p + 12);
        u16x8 w0, w1;
        w0[0]=f2bf(x0[0]); w0[1]=f2bf(x0[1]); w0[2]=f2bf(x0[2]); w0[3]=f2bf(x0[3]);
        w0[4]=f2bf(x1[0]); w0[5]=f2bf(x1[1]); w0[6]=f2bf(x1[2]); w0[7]=f2bf(x1[3]);
        w1[0]=f2bf(x2[0]); w1[1]=f2bf(x2[1]); w1[2]=f2bf(x2[2]); w1[3]=f2bf(x2[3]);
        w1[4]=f2bf(x3[0]); w1[5]=f2bf(x3[1]); w1[6]=f2bf(x3[2]); w1[7]=f2bf(x3[3]);
        *(u16x8*)&Ks[kr * LDK + kc0]     = w0;
        *(u16x8*)&Ks[kr * LDK + kc0 + 8] = w1;
    }
    // ---- stage V^T [e][pos] ----
#pragma unroll
    for (int i = 0; i < 2; ++i) {
        const int pos0 = wv * 8 + i * 32;
        const float* p = vp + (size_t)pos0 * DHEAD + ln;
        u16x8 t;
#pragma unroll
        for (int j = 0; j < 8; ++j) t[j] = f2bf(p[(size_t)j * DHEAD]);
        *(u16x8*)&Vt[ln * LDK + pos0] = t;
    }
    // ---- stage S^T chunk (8 KB bf16, straight coalesced copy) ----
    {
        const size_t sb = ((size_t)(bh * NC + c) << 12) + (size_t)tid * 16;
        const int r = tid >> 2, ccol = (tid & 3) * 16;
        *(u16x8*)&ShL[r * LDK + ccol]     = *(const u16x8*)(Sg + sb);
        *(u16x8*)&ShL[r * LDK + ccol + 8] = *(const u16x8*)(Sg + sb + 8);
    }

    // ---- Q A-fragments ----
    bf16x8 aQ[2];
    {
        const float* qrow = qp + (size_t)(wv * 16 + lnlo) * DHEAD;
#pragma unroll
        for (int ks = 0; ks < 2; ++ks) {
            const float* p = qrow + ks * 32 + quad * 8;
            bf16x8 a;
#pragma unroll
            for (int j = 0; j < 8; ++j) a[j] = (short)f2bf(p[j]);
            aQ[ks] = a;
        }
    }
    float rf[4];
#pragma unroll
    for (int r = 0; r < 4; ++r) rf[r] = exp2f((float)(wv * 16 + quad * 4 + r) * sh);

    __syncthreads();   // barrier #1: staging complete

    // ---- intra scores first (feeds Ws writes ASAP) ----
    f32x4 acc[4];
#pragma unroll
    for (int nt = 0; nt < 4; ++nt) {
        f32x4 a = (f32x4){0.f, 0.f, 0.f, 0.f};
#pragma unroll
        for (int ks = 0; ks < 2; ++ks) {
            const bf16x8 bk = *(const bf16x8*)&Ks[(nt * 16 + lnlo) * LDK + ks * 32 + quad * 8];
            a = __builtin_amdgcn_mfma_f32_16x16x32_bf16(aQ[ks], bk, a, 0, 0, 0);
        }
        acc[nt] = a;
    }

    // ---- decay*scale*causal -> Ws (dedicated region; same-wave-slab RAW only,
    //      no barrier: lane writes rows wv*16+quad*4+r, reads row wv*16+lnlo) ----
#pragma unroll
    for (int nt = 0; nt < 4; ++nt) {
        const int jn = nt * 16 + lnlo;
        const float cf = scale * exp2f(-(float)jn * sh);
#pragma unroll
        for (int r = 0; r < 4; ++r) {
            const int ri = wv * 16 + quad * 4 + r;
            float wgt = acc[nt][r] * rf[r] * cf;
            if (ri < jn) wgt = 0.0f;
            Ws[ri * LDK + jn] = f2bf(wgt);
        }
    }

    // ---- cross: o = Q.S (independent of Ws; hides Ws ds-write latency) ----
    f32x4 o[4];
#pragma unroll
    for (int nt = 0; nt < 4; ++nt) {
        f32x4 a = (f32x4){0.f, 0.f, 0.f, 0.f};
#pragma unroll
        for (int ks = 0; ks < 2; ++ks) {
            const bf16x8 bs = *(const bf16x8*)&ShL[(nt * 16 + lnlo) * LDK + ks * 32 + quad * 8];
            a = __builtin_amdgcn_mfma_f32_16x16x32_bf16(aQ[ks], bs, a, 0, 0, 0);
        }
        o[nt] = a;
    }
#pragma unroll
    for (int nt = 0; nt < 4; ++nt)
#pragma unroll
        for (int r = 0; r < 4; ++r) o[nt][r] *= rf[r] * scale;

    const bf16x8 aW0 = *(const bf16x8*)&Ws[(wv * 16 + lnlo) * LDK + quad * 8];
    const bf16x8 aW1 = *(const bf16x8*)&Ws[(wv * 16 + lnlo) * LDK + 32 + quad * 8];

    // ---- O += P V ----
#pragma unroll
    for (int nt = 0; nt < 4; ++nt) {
        const bf16x8 bv0 = *(const bf16x8*)&Vt[(nt * 16 + lnlo) * LDK + quad * 8];
        const bf16x8 bv1 = *(const bf16x8*)&Vt[(nt * 16 + lnlo) * LDK + 32 + quad * 8];
        o[nt] = __builtin_amdgcn_mfma_f32_16x16x32_bf16(aW0, bv0, o[nt], 0, 0, 0);
        o[nt] = __builtin_amdgcn_mfma_f32_16x16x32_bf16(aW1, bv1, o[nt], 0, 0, 0);
    }

    // ---- epilogue: bounce through LDS (Ks+Vt dead) -> coalesced dwordx4 ----
    __syncthreads();   // barrier #2: all waves done with Ks/Vt MFMAs before overlay
    float* const Of = (float*)smem;   // 64 x 68 fp32 = 17408 B (< Ks+Vt = 18432 B)
#pragma unroll
    for (int nt = 0; nt < 4; ++nt)
#pragma unroll
        for (int r = 0; r < 4; ++r)
            Of[(wv * 16 + quad * 4 + r) * 68 + nt * 16 + lnlo] = o[nt][r];
    // rows [wv*16, wv*16+16) written and read by the same wave -> no barrier
    {
        const int row = tid >> 2, col0 = (tid & 3) * 16;
        const float* src = &Of[row * 68 + col0];
        float* dst = op + (size_t)row * DHEAD + col0;
        *(f32x4*)(dst + 0)  = *(const f32x4*)(src + 0);
        *(f32x4*)(dst + 4)  = *(const f32x4*)(src + 4);
        *(f32x4*)(dst + 8)  = *(const f32x4*)(src + 8);
        *(f32x4*)(dst + 12) = *(const f32x4*)(src + 12);
    }
}

extern "C" void kernel_launch(void* const* d_in, const int* in_sizes, int n_in,
                              void* d_out, int out_size, void* d_ws, size_t ws_size,
                              hipStream_t stream) {
    (void)in_sizes; (void)n_in; (void)out_size; (void)ws_size;
    const float* q = (const float*)d_in[0];
    const float* k = (const float*)d_in[1];
    const float* v = (const float*)d_in[2];
    float* o  = (float*)d_out;
    unsigned short* Ug = (unsigned short*)d_ws;                                        // 8 MB bf16
    unsigned short* Sg = (unsigned short*)((char*)d_ws + (size_t)BH * NC * 4096 * 2);  // 8 MB bf16

    dim3 blk(256, 1, 1);
    ret_p1<<<dim3(NC - 1, BH, 1), blk, 0, stream>>>(k, v, Ug);   // U_31 never consumed
    ret_p2<<<dim3(16, BH, 1), blk, 0, stream>>>(Ug, Sg);
    ret_p3<<<dim3(NC, BH, 1), blk, 0, stream>>>(q, k, v, Sg, o);
}